// Round 12
// baseline (347.690 us; speedup 1.0000x reference)
//
#include <hip/hip_runtime.h>

namespace {

typedef float v4f __attribute__((ext_vector_type(4)));
typedef float v2f __attribute__((ext_vector_type(2)));

constexpr int   kB     = 32768;
constexpr int   kT     = 50;
constexpr float kDT    = 0.01f;
constexpr float kGamma = 0.1f;
constexpr float kSigma = 0.2f;
constexpr float kTau   = 0.5f;

// Packed-weight workspace layout (float offsets). All v2f reads 8B-aligned.
constexpr int WS_L1  = 0;              // [2 mlps][10 rows][20]  b, w_t, wx0..15, pad2
constexpr int WS_L2  = WS_L1  + 400;   // [2][10][12]            b, 0, w0..9
constexpr int WS_L3  = WS_L2  + 240;   // [24][12] rows: q0 zv0-7, q1 zv8-15, q2 u0-3, q3 u4-7
constexpr int WS_UPD = WS_L3  + 288;   // [16][80]  Arow16 Brow8 Crow16 Drow8 Acol16 Ccol16
constexpr int WS_DH  = WS_UPD + 1280;  // [8][32]   Bcol16 Dcol16

__device__ __forceinline__ float ftanh(float x) {
  float e = exp2f(x * 2.8853900817779268f);   // exp(2x) via exp2
  return 1.0f - 2.0f * __builtin_amdgcn_rcpf(e + 1.0f);
}

__device__ __forceinline__ v2f lo2(v4f a) { return __builtin_shufflevector(a, a, 0, 1); }
__device__ __forceinline__ v2f hi2(v4f a) { return __builtin_shufflevector(a, a, 2, 3); }

// Forced packed-fp32 FMA: acc.lo += w.lo*x.lo, acc.hi += w.hi*x.hi.
// Weights are wave-uniform (scalar-loaded) -> SGPR-pair operand (VOP3P allows
// one scalar src); acc/x in VGPR pairs. R10 showed the backend scalarizes
// plain v2f arithmetic (1650 VALU instr/wave-step vs ~900 packed estimate).
__device__ __forceinline__ void pk_fma(v2f& acc, v2f w, v2f x) {
  asm("v_pk_fma_f32 %0, %1, %2, %0" : "+v"(acc) : "s"(w), "v"(x));
}

// ---------------- prep: pack weights in per-wave consumption order ----------
__global__ __launch_bounds__(256) void prep_kernel(
    const float* __restrict__ A,   const float* __restrict__ Bm,
    const float* __restrict__ Cm,  const float* __restrict__ Dm,
    const float* __restrict__ pW1, const float* __restrict__ pb1,
    const float* __restrict__ pW2, const float* __restrict__ pb2,
    const float* __restrict__ pW3, const float* __restrict__ pb3,
    const float* __restrict__ zW1, const float* __restrict__ zb1,
    const float* __restrict__ zW2, const float* __restrict__ zb2,
    const float* __restrict__ zW3, const float* __restrict__ zb3,
    float* __restrict__ ws, float* __restrict__ out)
{
  const int tid = threadIdx.x;
  if (tid < 2) out[tid] = 0.0f;   // harness re-poisons out each replay
  // L1: m=0 -> z rows 0..9 ; m=1 -> phi rows 0..9
  for (int c = tid; c < 20; c += 256) {
    int m = c / 10, row = c % 10;
    const float* W = m ? pW1 : zW1;
    const float* b = m ? pb1 : zb1;
    float* d = ws + WS_L1 + c * 20;
    d[0] = b[row];
    for (int k = 0; k < 17; ++k) d[1 + k] = W[k * 10 + row];
    d[18] = 0.f; d[19] = 0.f;
  }
  // L2: [b, 0, w0..9]
  for (int c = tid; c < 20; c += 256) {
    int m = c / 10, row = c % 10;
    const float* W = m ? pW2 : zW2;
    const float* b = m ? pb2 : zb2;
    float* d = ws + WS_L2 + c * 12;
    d[0] = b[row]; d[1] = 0.f;
    for (int k = 0; k < 10; ++k) d[2 + k] = W[k * 10 + row];
  }
  // L3: [b, 0, w0..9]; rows 0..15 zv, 16..23 u
  for (int c = tid; c < 24; c += 256) {
    float* d = ws + WS_L3 + c * 12;
    d[1] = 0.f;
    if (c < 16) {
      d[0] = zb3[c];
      for (int k = 0; k < 10; ++k) d[2 + k] = zW3[k * 16 + c];
    } else {
      int row = c - 16;
      d[0] = pb3[row];
      for (int k = 0; k < 10; ++k) d[2 + k] = pW3[k * 8 + row];
    }
  }
  // UPD: per state row i: A row, B row, C row, D row, A col, C col
  for (int i = tid; i < 16; i += 256) {
    float* d = ws + WS_UPD + i * 80;
    for (int j = 0; j < 16; ++j) d[j]      = A [i * 16 + j];
    for (int j = 0; j < 8;  ++j) d[16 + j] = Bm[i * 8  + j];
    for (int j = 0; j < 16; ++j) d[24 + j] = Cm[i * 16 + j];
    for (int j = 0; j < 8;  ++j) d[40 + j] = Dm[i * 8  + j];
    for (int j = 0; j < 16; ++j) d[48 + j] = A [j * 16 + i];
    for (int j = 0; j < 16; ++j) d[64 + j] = Cm[j * 16 + i];
  }
  // DH: per control row i: B col, D col
  for (int i = tid; i < 8; i += 256) {
    float* d = ws + WS_DH + i * 32;
    for (int j = 0; j < 16; ++j) d[j]      = Bm[j * 8 + i];
    for (int j = 0; j < 16; ++j) d[16 + j] = Dm[j * 8 + i];
  }
}

// Wave-specialized UPD + dH, forced packed-fp32.
template <int Q>
__device__ __forceinline__ void upd_body(
    const float* __restrict__ Wup, const float* __restrict__ Wdh,
    const v4f x4[4], const v4f y4[4], const v4f zvf[4], const v4f uff[2],
    float dwv, float* __restrict__ Xn, float* __restrict__ Yn, float& s2)
{
  v2f x2[8], y2[8], z2[8], u2[4];
#pragma unroll
  for (int c = 0; c < 4; ++c) {
    x2[2 * c] = lo2(x4[c]);  x2[2 * c + 1] = hi2(x4[c]);
    y2[2 * c] = lo2(y4[c]);  y2[2 * c + 1] = hi2(y4[c]);
    z2[2 * c] = lo2(zvf[c]); z2[2 * c + 1] = hi2(zvf[c]);
  }
#pragma unroll
  for (int c = 0; c < 2; ++c) { u2[2 * c] = lo2(uff[c]); u2[2 * c + 1] = hi2(uff[c]); }

#pragma unroll
  for (int r = 0; r < 4; ++r) {
    const float* w = Wup + r * 80;        // state row i = 4Q + r
    v2f dx = {kGamma, 0.f}, fx = {kSigma, 0.f};
#pragma unroll
    for (int c = 0; c < 8; ++c) {
      pk_fma(dx, *(const v2f*)(w + 2 * c),      x2[c]);
      pk_fma(fx, *(const v2f*)(w + 24 + 2 * c), x2[c]);
    }
#pragma unroll
    for (int c = 0; c < 4; ++c) {
      pk_fma(dx, *(const v2f*)(w + 16 + 2 * c), u2[c]);
      pk_fma(fx, *(const v2f*)(w + 40 + 2 * c), u2[c]);
    }
    const float xi = x4[Q][r];
    const float yi = y4[Q][r];
    const float zi = zvf[Q][r];
    v2f dy = {xi, 0.f};
#pragma unroll
    for (int c = 0; c < 8; ++c) {
      pk_fma(dy, *(const v2f*)(w + 48 + 2 * c), y2[c]);
      pk_fma(dy, *(const v2f*)(w + 64 + 2 * c), z2[c]);
    }
    Xn[r] = xi + kDT * (dx[0] + dx[1]) + dwv * (fx[0] + fx[1]);
    Yn[r] = yi - kDT * (dy[0] + dy[1]) + dwv * zi;
  }
#pragma unroll
  for (int r = 0; r < 2; ++r) {
    const int i = 2 * Q + r;
    const float* w = Wdh + i * 32;
    v2f dh = {uff[i >> 2][i & 3], 0.f};
#pragma unroll
    for (int c = 0; c < 8; ++c) {
      pk_fma(dh, *(const v2f*)(w + 2 * c),      y2[c]);
      pk_fma(dh, *(const v2f*)(w + 16 + 2 * c), z2[c]);
    }
    const float d = dh[0] + dh[1];
    s2 += d * d;
  }
}

// ---------------- main: 4 waves / 64 elements, 2 barriers per step ----------
__global__ __launch_bounds__(256)
__attribute__((amdgpu_waves_per_eu(2, 2)))
void bsde_kernel(
    const float* __restrict__ dw,  const float* __restrict__ X0,
    const float* __restrict__ yW1, const float* __restrict__ yb1,
    const float* __restrict__ yW2, const float* __restrict__ yb2,
    const float* __restrict__ yW3, const float* __restrict__ yb3,
    const float* __restrict__ ws,  float* __restrict__ out)
{
  __shared__ float XYt[64][36];   // dwords 0..15 = X, 16..31 = Y
  __shared__ float ZUt[64][28];   // 0..15 = Zv, 16..23 = u

  const int lane = threadIdx.x & 63;
  const int q    = __builtin_amdgcn_readfirstlane((int)(threadIdx.x >> 6));
  const int e    = blockIdx.x * 64 + lane;

  const int m      = q >> 1;                                   // 0=z, 1=phi
  const int l3off  = (q & 2) ? (192 + (q & 1) * 48) : (q * 96);
  const float* Wl1 = ws + WS_L1  + m * 200;
  const float* Wl2 = ws + WS_L2  + m * 120;
  const float* Wl3 = ws + WS_L3  + l3off;
  const float* Wup = ws + WS_UPD + q * 320;
  const float* Wdh = ws + WS_DH;

  // ---- X0 load (b128) + Y0 MLP (redundant per wave, one-time) ----
  v4f x4[4], y4[4];
#pragma unroll
  for (int c = 0; c < 4; ++c) x4[c] = *(const v4f*)&X0[e * 16 + 4 * c];

  {
    float h1t[10], h2t[10];
#pragma unroll
    for (int r = 0; r < 10; ++r) {
      float s = yb1[r];
#pragma unroll
      for (int c = 0; c < 4; ++c)
#pragma unroll
        for (int j = 0; j < 4; ++j) s += x4[c][j] * yW1[(4 * c + j) * 10 + r];
      h1t[r] = ftanh(s);
    }
#pragma unroll
    for (int r = 0; r < 10; ++r) {
      float s = yb2[r];
#pragma unroll
      for (int k = 0; k < 10; ++k) s += h1t[k] * yW2[k * 10 + r];
      h2t[r] = ftanh(s);
    }
#pragma unroll
    for (int r = 0; r < 16; ++r) {
      float s = yb3[r];
#pragma unroll
      for (int k = 0; k < 10; ++k) s += h2t[k] * yW3[k * 16 + r];
      y4[r >> 2][r & 3] = s;
    }
  }

  // Seed XYt (wave 0 only; values bit-identical across waves), then barrier.
  if (q == 0) {
#pragma unroll
    for (int c = 0; c < 4; ++c) {
      *(v4f*)&XYt[lane][4 * c]      = x4[c];
      *(v4f*)&XYt[lane][16 + 4 * c] = y4[c];
    }
  }
  __syncthreads();

  float lcp = 0.0f;
  float Xn[4], Yn[4];
  float dwv = dw[e];   // t=0 increment

  // ------------------------------- time loop -------------------------------
#pragma unroll 1
  for (int t = 0; t < kT; ++t) {
    float dwn = (t < kT - 1) ? dw[(t + 1) * kB + e] : 0.0f;
    const float tv = (float)t * kDT;
    const float wt = (t == 0 || t == kT - 1) ? 1.0f : 2.0f;

    // Read full state (b128), pin in registers.
#pragma unroll
    for (int c = 0; c < 4; ++c) {
      x4[c] = *(const v4f*)&XYt[lane][4 * c];
      y4[c] = *(const v4f*)&XYt[lane][16 + 4 * c];
    }
    asm volatile("" : "+v"(x4[0]), "+v"(x4[1]), "+v"(x4[2]), "+v"(x4[3]),
                      "+v"(y4[0]), "+v"(y4[1]), "+v"(y4[2]), "+v"(y4[3]));

    v2f xp[8];
#pragma unroll
    for (int c = 0; c < 4; ++c) { xp[2 * c] = lo2(x4[c]); xp[2 * c + 1] = hi2(x4[c]); }

    // L1: full 10 rows of own MLP (8 pk_fma per row)
    float hh[10];
#pragma unroll
    for (int r = 0; r < 10; ++r) {
      const float* w = Wl1 + r * 20;
      v2f bw = *(const v2f*)w;                 // [bias, w_t]
      v2f acc = {bw[0] + tv * bw[1], 0.f};
#pragma unroll
      for (int c = 0; c < 8; ++c) pk_fma(acc, *(const v2f*)(w + 2 + 2 * c), xp[c]);
      hh[r] = ftanh(acc[0] + acc[1]);
    }
    v2f hp[5];
#pragma unroll
    for (int k = 0; k < 5; ++k) { v2f t2 = {hh[2 * k], hh[2 * k + 1]}; hp[k] = t2; }

    // L2: full 10 rows (5 pk each)
    float gg[10];
#pragma unroll
    for (int r = 0; r < 10; ++r) {
      const float* w = Wl2 + r * 12;
      v2f acc = {w[0], 0.f};
#pragma unroll
      for (int k = 0; k < 5; ++k) pk_fma(acc, *(const v2f*)(w + 2 + 2 * k), hp[k]);
      gg[r] = ftanh(acc[0] + acc[1]);
    }
    v2f gp[5];
#pragma unroll
    for (int k = 0; k < 5; ++k) { v2f t2 = {gg[2 * k], gg[2 * k + 1]}; gp[k] = t2; }

    // L3: z-waves 8 Zv rows each; phi-waves 4 u rows each
    if (q < 2) {
      float z[8];
#pragma unroll
      for (int r = 0; r < 8; ++r) {
        const float* w = Wl3 + r * 12;
        v2f acc = {w[0], 0.f};
#pragma unroll
        for (int k = 0; k < 5; ++k) pk_fma(acc, *(const v2f*)(w + 2 + 2 * k), gp[k]);
        z[r] = acc[0] + acc[1];
      }
      v4f z0 = {z[0], z[1], z[2], z[3]}, z1 = {z[4], z[5], z[6], z[7]};
      *(v4f*)&ZUt[lane][8 * q]     = z0;
      *(v4f*)&ZUt[lane][8 * q + 4] = z1;
    } else {
      float z[4];
#pragma unroll
      for (int r = 0; r < 4; ++r) {
        const float* w = Wl3 + r * 12;
        v2f acc = {w[0], 0.f};
#pragma unroll
        for (int k = 0; k < 5; ++k) pk_fma(acc, *(const v2f*)(w + 2 + 2 * k), gp[k]);
        z[r] = acc[0] + acc[1];
      }
      v4f zz = {z[0], z[1], z[2], z[3]};
      *(v4f*)&ZUt[lane][16 + 4 * (q - 2)] = zz;
    }
    __syncthreads();                       // B1: ZU visible

    v4f zvf[4], uff[2];
#pragma unroll
    for (int c = 0; c < 4; ++c) zvf[c] = *(const v4f*)&ZUt[lane][4 * c];
#pragma unroll
    for (int c = 0; c < 2; ++c) uff[c] = *(const v4f*)&ZUt[lane][16 + 4 * c];
    asm volatile("" : "+v"(zvf[0]), "+v"(zvf[1]), "+v"(zvf[2]), "+v"(zvf[3]),
                      "+v"(uff[0]), "+v"(uff[1]));

    // UPD + dH, wave-specialized (uniform branch)
    float s2 = 0.0f;
    if      (q == 0) upd_body<0>(Wup, Wdh, x4, y4, zvf, uff, dwv, Xn, Yn, s2);
    else if (q == 1) upd_body<1>(Wup, Wdh, x4, y4, zvf, uff, dwv, Xn, Yn, s2);
    else if (q == 2) upd_body<2>(Wup, Wdh, x4, y4, zvf, uff, dwv, Xn, Yn, s2);
    else             upd_body<3>(Wup, Wdh, x4, y4, zvf, uff, dwv, Xn, Yn, s2);
    lcp += (0.5f * kDT * kTau * kTau) * wt * s2;

    // Publish own rows (b128)
    {
      v4f xs = {Xn[0], Xn[1], Xn[2], Xn[3]};
      v4f ys = {Yn[0], Yn[1], Yn[2], Yn[3]};
      *(v4f*)&XYt[lane][4 * q]      = xs;
      *(v4f*)&XYt[lane][16 + 4 * q] = ys;
    }
    dwv = dwn;
    __syncthreads();                       // B2: XY visible
  }

  // ---- losses ----
#pragma unroll
  for (int c = 0; c < 4; ++c) {
    x4[c] = *(const v4f*)&XYt[lane][4 * c];
    y4[c] = *(const v4f*)&XYt[lane][16 + 4 * c];
  }
  float bp = 0.0f;
  if (q == 0) {
#pragma unroll
    for (int c = 0; c < 4; ++c)
#pragma unroll
      for (int j = 0; j < 4; ++j) {
        float d = y4[c][j] - x4[c][j];
        bp += d * d;
      }
  }
#pragma unroll
  for (int s = 32; s > 0; s >>= 1) {
    bp  += __shfl_down(bp,  s, 64);
    lcp += __shfl_down(lcp, s, 64);
  }
  if (lane == 0) {
    if (q == 0) atomicAdd(&out[0], bp * (1.0f / (float)kB));
    atomicAdd(&out[1], lcp * (1.0f / (float)kB));
  }
}

} // namespace

extern "C" void kernel_launch(void* const* d_in, const int* in_sizes, int n_in,
                              void* d_out, int out_size, void* d_ws, size_t ws_size,
                              hipStream_t stream) {
  (void)in_sizes; (void)n_in; (void)ws_size; (void)out_size;

  const float* dw  = (const float*)d_in[0];
  const float* X0  = (const float*)d_in[1];
  const float* A   = (const float*)d_in[2];
  const float* Bm  = (const float*)d_in[3];
  const float* Cm  = (const float*)d_in[4];
  const float* Dm  = (const float*)d_in[5];
  const float* pW1 = (const float*)d_in[6];
  const float* pb1 = (const float*)d_in[7];
  const float* pW2 = (const float*)d_in[8];
  const float* pb2 = (const float*)d_in[9];
  const float* pW3 = (const float*)d_in[10];
  const float* pb3 = (const float*)d_in[11];
  const float* zW1 = (const float*)d_in[12];
  const float* zb1 = (const float*)d_in[13];
  const float* zW2 = (const float*)d_in[14];
  const float* zb2 = (const float*)d_in[15];
  const float* zW3 = (const float*)d_in[16];
  const float* zb3 = (const float*)d_in[17];
  const float* yW1 = (const float*)d_in[18];
  const float* yb1 = (const float*)d_in[19];
  const float* yW2 = (const float*)d_in[20];
  const float* yb2 = (const float*)d_in[21];
  const float* yW3 = (const float*)d_in[22];
  const float* yb3 = (const float*)d_in[23];
  float* out = (float*)d_out;
  float* ws  = (float*)d_ws;

  prep_kernel<<<1, 256, 0, stream>>>(
      A, Bm, Cm, Dm,
      pW1, pb1, pW2, pb2, pW3, pb3,
      zW1, zb1, zW2, zb2, zW3, zb3, ws, out);

  bsde_kernel<<<kB / 64, 256, 0, stream>>>(
      dw, X0, yW1, yb1, yW2, yb2, yW3, yb3, ws, out);
}

// Round 13
// 218.908 us; speedup vs baseline: 1.5883x; 1.5883x over previous
//
#include <hip/hip_runtime.h>

namespace {

typedef float v4f __attribute__((ext_vector_type(4)));
typedef _Float16 half8 __attribute__((ext_vector_type(8)));
typedef unsigned int uint32;

constexpr int   kB     = 32768;
constexpr int   kT     = 50;
constexpr float kDT    = 0.01f;
constexpr float kGamma = 0.1f;
constexpr float kSigma = 0.2f;
constexpr float kTau   = 0.5f;

// 13 MFMA A-fragment images, each [64 lanes][4 dwords] f16 (lane: m=l&15,
// quad=l>>4 holds W[m][8q..8q+7]).  Phases:
// 0 y0L1  1 y0L2  2 y0L3  3 L1z  4 L1p  5 L2z  6 L2p  7 L3z  8 L3p
// 9 dx [A|B|γ]  10 fx [C|D|σ]  11 dy [Acol|Ccol]  12 dH [Bcol|Dcol]
constexpr int kWsDwords = 13 * 256;

__device__ __forceinline__ float ftanh(float x) {
  float e = exp2f(x * 2.8853900817779268f);
  return 1.0f - 2.0f * __builtin_amdgcn_rcpf(e + 1.0f);
}

__device__ __forceinline__ uint32 pk2(float a, float b) {
  union { _Float16 h[2]; uint32 u; } z;
  z.h[0] = (_Float16)a; z.h[1] = (_Float16)b;
  return z.u;
}

__device__ __forceinline__ v4f tanh4(v4f a) {
  v4f r;
  r[0] = ftanh(a[0]); r[1] = ftanh(a[1]);
  r[2] = ftanh(a[2]); r[3] = ftanh(a[3]);
  return r;
}

#define WAVE_FENCE() asm volatile("" ::: "memory")

// ---------------- prep: build A-fragment images (f16) -----------------------
__global__ __launch_bounds__(256) void prep_kernel(
    const float* __restrict__ A,   const float* __restrict__ Bm,
    const float* __restrict__ Cm,  const float* __restrict__ Dm,
    const float* __restrict__ pW1, const float* __restrict__ pb1,
    const float* __restrict__ pW2, const float* __restrict__ pb2,
    const float* __restrict__ pW3, const float* __restrict__ pb3,
    const float* __restrict__ zW1, const float* __restrict__ zb1,
    const float* __restrict__ zW2, const float* __restrict__ zb2,
    const float* __restrict__ zW3, const float* __restrict__ zb3,
    const float* __restrict__ yW1, const float* __restrict__ yb1,
    const float* __restrict__ yW2, const float* __restrict__ yb2,
    const float* __restrict__ yW3, const float* __restrict__ yb3,
    uint32* __restrict__ ws, float* __restrict__ out)
{
  const int tid = threadIdx.x;
  if (tid < 2) out[tid] = 0.0f;

  auto wval = [&](int p, int m, int k) -> float {
    switch (p) {
      case 0:  // y0 L1: s=[t,1,x0..15]; no t input
        if (m >= 10) return 0.f;
        if (k == 1) return yb1[m];
        if (k >= 2 && k < 18) return yW1[(k - 2) * 10 + m];
        return 0.f;
      case 1:
        if (m >= 10) return 0.f;
        if (k < 10) return yW2[k * 10 + m];
        if (k == 10) return yb2[m];
        return 0.f;
      case 2:
        if (k < 10) return yW3[k * 16 + m];
        if (k == 10) return yb3[m];
        return 0.f;
      case 3:  // L1z: s=[t,1,x]; W1 row0 = t
        if (m >= 10) return 0.f;
        if (k == 0) return zW1[m];
        if (k == 1) return zb1[m];
        if (k < 18) return zW1[(k - 1) * 10 + m];
        return 0.f;
      case 4:
        if (m >= 10) return 0.f;
        if (k == 0) return pW1[m];
        if (k == 1) return pb1[m];
        if (k < 18) return pW1[(k - 1) * 10 + m];
        return 0.f;
      case 5:
        if (m >= 10) return 0.f;
        if (k < 10) return zW2[k * 10 + m];
        if (k == 10) return zb2[m];
        return 0.f;
      case 6:
        if (m >= 10) return 0.f;
        if (k < 10) return pW2[k * 10 + m];
        if (k == 10) return pb2[m];
        return 0.f;
      case 7:
        if (k < 10) return zW3[k * 16 + m];
        if (k == 10) return zb3[m];
        return 0.f;
      case 8:
        if (m >= 8) return 0.f;
        if (k < 10) return pW3[k * 8 + m];
        if (k == 10) return pb3[m];
        return 0.f;
      case 9:  // dx: s=[x0..15,u0..7,1,...]
        if (k < 16) return A[m * 16 + k];
        if (k < 24) return Bm[m * 8 + (k - 16)];
        if (k == 24) return kGamma;
        return 0.f;
      case 10:
        if (k < 16) return Cm[m * 16 + k];
        if (k < 24) return Dm[m * 8 + (k - 16)];
        if (k == 24) return kSigma;
        return 0.f;
      case 11: // dy: s=[y0..15,zv0..15]
        if (k < 16) return A[k * 16 + m];
        return Cm[(k - 16) * 16 + m];
      case 12:
        if (m >= 8) return 0.f;
        if (k < 16) return Bm[k * 8 + m];
        return Dm[(k - 16) * 8 + m];
    }
    return 0.f;
  };

  for (int idx = tid; idx < kWsDwords; idx += 256) {
    int p = idx >> 8, r = idx & 255;
    int lane = r >> 2, dwi = r & 3;
    int m = lane & 15, q = lane >> 4;
    int k0 = 8 * q + 2 * dwi;
    ws[idx] = pk2(wval(p, m, k0), wval(p, m, k0 + 1));
  }
}

// ---------------- main: MFMA-f16, 16 elements/wave, barrier-free ------------
// State vectors live in LDS as f16 [elem][32 slots = 16 dwords] (stride 20).
// X,Y trajectories stay fp32 in C-layout registers; only MFMA inputs are f16.
__global__ __launch_bounds__(64)
__attribute__((amdgpu_waves_per_eu(2, 2)))
void bsde_kernel(const float* __restrict__ dw, const float* __restrict__ X0,
                 const uint32* __restrict__ wsu, float* __restrict__ out)
{
  // Buffers: 0=SB1 [t,1,x], 1=HZ, 2=HP, 3=GZ, 4=GP (h/g: [h0..9,1,0..]),
  // 5=XU [x,u,1,0..], 6=YZ [y,zv]
  __shared__ __align__(16) uint32 S[7][16][20];
  constexpr int B1 = 0, HZ = 1, HP = 2, GZ = 3, GP = 4, XU = 5, YZ = 6;

  const int lane = threadIdx.x;
  const int col  = lane & 15;        // element within block
  const int quad = lane >> 4;
  const int e    = blockIdx.x * 16 + col;

  // A-fragments -> registers (persist whole kernel)
  half8 af[13];
#pragma unroll
  for (int p = 0; p < 13; ++p) {
    union { uint4 u; half8 h; } z;
    z.u = *(const uint4*)(wsu + p * 256 + lane * 4);
    af[p] = z.h;
  }

  auto readB = [&](int b) -> half8 {
    union { uint4 u; half8 h; } z;
    z.u = *(const uint4*)&S[b][col][4 * quad];
    return z.h;
  };
  // h/g writer: rows 0-9 valid + bias slot s10=1
  auto writeH = [&](int b, v4f t) {
    if (quad < 2) {
      uint2 w = {pk2(t[0], t[1]), pk2(t[2], t[3])};
      *(uint2*)&S[b][col][2 * quad] = w;
    } else if (quad == 2) {
      uint2 w = {pk2(t[0], t[1]), pk2(1.f, 0.f)};
      *(uint2*)&S[b][col][4] = w;
    }
  };

  // ---- init: zero LDS, constants, X0 ----
  for (int i = lane; i < 7 * 16 * 20; i += 64) (&S[0][0][0])[i] = 0u;
  WAVE_FENCE();

  v4f x4 = *(const v4f*)&X0[e * 16 + 4 * quad];   // C-layout: row=4*quad+r
  {
    uint32 p01 = pk2(x4[0], x4[1]), p23 = pk2(x4[2], x4[3]);
    S[B1][col][1 + 2 * quad] = p01;
    S[B1][col][2 + 2 * quad] = p23;
    uint2 w = {p01, p23};
    *(uint2*)&S[XU][col][2 * quad] = w;
    if (lane < 16) {
      S[B1][col][0]  = pk2(0.f, 1.f);   // t=0, const-1
      S[XU][col][12] = pk2(1.f, 0.f);   // const-1 slot (k=24)
    }
  }
  WAVE_FENCE();

  const v4f zero4 = {0.f, 0.f, 0.f, 0.f};

  // ---- Y0 MLP via MFMA (phases 0,1,2) ----
  v4f y4;
  {
    v4f d = __builtin_amdgcn_mfma_f32_16x16x32_f16(af[0], readB(B1), zero4, 0, 0, 0);
    writeH(HZ, tanh4(d));
    WAVE_FENCE();
    d = __builtin_amdgcn_mfma_f32_16x16x32_f16(af[1], readB(HZ), zero4, 0, 0, 0);
    writeH(GZ, tanh4(d));
    WAVE_FENCE();
    y4 = __builtin_amdgcn_mfma_f32_16x16x32_f16(af[2], readB(GZ), zero4, 0, 0, 0);
    uint2 w = {pk2(y4[0], y4[1]), pk2(y4[2], y4[3])};
    *(uint2*)&S[YZ][col][2 * quad] = w;
  }
  WAVE_FENCE();

  float lcp = 0.0f;
  float dwv = dw[e];   // t=0

  // ------------------------------- time loop -------------------------------
#pragma unroll 1
  for (int t = 0; t < kT; ++t) {
    float dwn = (t < kT - 1) ? dw[(t + 1) * kB + e] : 0.0f;
    const float tv = (float)t * kDT;
    const float wt = (t == 0 || t == kT - 1) ? 1.0f : 2.0f;

    if (lane < 16) S[B1][col][0] = pk2(tv, 1.f);
    WAVE_FENCE();

    // L1 both MLPs from shared state read
    half8 bs = readB(B1);
    v4f hz = __builtin_amdgcn_mfma_f32_16x16x32_f16(af[3], bs, zero4, 0, 0, 0);
    v4f hp = __builtin_amdgcn_mfma_f32_16x16x32_f16(af[4], bs, zero4, 0, 0, 0);
    writeH(HZ, tanh4(hz));
    writeH(HP, tanh4(hp));
    WAVE_FENCE();

    // L2
    v4f gz = __builtin_amdgcn_mfma_f32_16x16x32_f16(af[5], readB(HZ), zero4, 0, 0, 0);
    v4f gp = __builtin_amdgcn_mfma_f32_16x16x32_f16(af[6], readB(HP), zero4, 0, 0, 0);
    writeH(GZ, tanh4(gz));
    writeH(GP, tanh4(gp));
    WAVE_FENCE();

    // L3: zv (16 rows, C-layout regs + LDS), u (8 rows; rows 8-15 are 0)
    v4f zv = __builtin_amdgcn_mfma_f32_16x16x32_f16(af[7], readB(GZ), zero4, 0, 0, 0);
    v4f uu = __builtin_amdgcn_mfma_f32_16x16x32_f16(af[8], readB(GP), zero4, 0, 0, 0);
    {
      uint2 wz = {pk2(zv[0], zv[1]), pk2(zv[2], zv[3])};
      *(uint2*)&S[YZ][col][8 + 2 * quad] = wz;
      if (quad < 2) {
        uint2 wu = {pk2(uu[0], uu[1]), pk2(uu[2], uu[3])};
        *(uint2*)&S[XU][col][8 + 2 * quad] = wu;
      }
    }
    WAVE_FENCE();

    // UPD + dH
    half8 bxu = readB(XU);
    half8 byz = readB(YZ);
    v4f dx = __builtin_amdgcn_mfma_f32_16x16x32_f16(af[9],  bxu, zero4, 0, 0, 0);
    v4f fx = __builtin_amdgcn_mfma_f32_16x16x32_f16(af[10], bxu, zero4, 0, 0, 0);
    v4f dy = __builtin_amdgcn_mfma_f32_16x16x32_f16(af[11], byz, zero4, 0, 0, 0);
    v4f dh = __builtin_amdgcn_mfma_f32_16x16x32_f16(af[12], byz, zero4, 0, 0, 0);

    float ss = 0.0f;
    v4f Xn, Yn;
#pragma unroll
    for (int r = 0; r < 4; ++r) {
      Xn[r] = x4[r] + kDT * dx[r] + dwv * fx[r];
      Yn[r] = y4[r] - kDT * (dy[r] + x4[r]) + dwv * zv[r];
      float d = dh[r] + uu[r];            // rows>=8: both 0
      ss += d * d;
    }
    lcp += (0.5f * kDT * kTau * kTau) * wt * ss;
    x4 = Xn; y4 = Yn;

    // publish next state (X -> SB1 + SXU, Y -> SYZ)
    {
      uint32 p01 = pk2(x4[0], x4[1]), p23 = pk2(x4[2], x4[3]);
      S[B1][col][1 + 2 * quad] = p01;
      S[B1][col][2 + 2 * quad] = p23;
      uint2 wx = {p01, p23};
      *(uint2*)&S[XU][col][2 * quad] = wx;
      uint2 wy = {pk2(y4[0], y4[1]), pk2(y4[2], y4[3])};
      *(uint2*)&S[YZ][col][2 * quad] = wy;
    }
    dwv = dwn;
    WAVE_FENCE();
  }

  // ---- losses: C-layout partials; 64-lane reduce covers 16 elems × 4 quads -
  float bp = 0.0f;
#pragma unroll
  for (int r = 0; r < 4; ++r) { float d = y4[r] - x4[r]; bp += d * d; }

#pragma unroll
  for (int s = 32; s > 0; s >>= 1) {
    bp  += __shfl_down(bp,  s, 64);
    lcp += __shfl_down(lcp, s, 64);
  }
  if (lane == 0) {
    atomicAdd(&out[0], bp  * (1.0f / (float)kB));
    atomicAdd(&out[1], lcp * (1.0f / (float)kB));
  }
}

} // namespace

extern "C" void kernel_launch(void* const* d_in, const int* in_sizes, int n_in,
                              void* d_out, int out_size, void* d_ws, size_t ws_size,
                              hipStream_t stream) {
  (void)in_sizes; (void)n_in; (void)ws_size; (void)out_size;

  const float* dw  = (const float*)d_in[0];
  const float* X0  = (const float*)d_in[1];
  const float* A   = (const float*)d_in[2];
  const float* Bm  = (const float*)d_in[3];
  const float* Cm  = (const float*)d_in[4];
  const float* Dm  = (const float*)d_in[5];
  const float* pW1 = (const float*)d_in[6];
  const float* pb1 = (const float*)d_in[7];
  const float* pW2 = (const float*)d_in[8];
  const float* pb2 = (const float*)d_in[9];
  const float* pW3 = (const float*)d_in[10];
  const float* pb3 = (const float*)d_in[11];
  const float* zW1 = (const float*)d_in[12];
  const float* zb1 = (const float*)d_in[13];
  const float* zW2 = (const float*)d_in[14];
  const float* zb2 = (const float*)d_in[15];
  const float* zW3 = (const float*)d_in[16];
  const float* zb3 = (const float*)d_in[17];
  const float* yW1 = (const float*)d_in[18];
  const float* yb1 = (const float*)d_in[19];
  const float* yW2 = (const float*)d_in[20];
  const float* yb2 = (const float*)d_in[21];
  const float* yW3 = (const float*)d_in[22];
  const float* yb3 = (const float*)d_in[23];
  float* out = (float*)d_out;
  unsigned int* ws = (unsigned int*)d_ws;

  prep_kernel<<<1, 256, 0, stream>>>(
      A, Bm, Cm, Dm,
      pW1, pb1, pW2, pb2, pW3, pb3,
      zW1, zb1, zW2, zb2, zW3, zb3,
      yW1, yb1, yW2, yb2, yW3, yb3, ws, out);

  bsde_kernel<<<kB / 16, 64, 0, stream>>>(dw, X0, ws, out);
}

// Round 14
// 216.841 us; speedup vs baseline: 1.6034x; 1.0095x over previous
//
#include <hip/hip_runtime.h>

namespace {

typedef float v4f __attribute__((ext_vector_type(4)));
typedef _Float16 half8 __attribute__((ext_vector_type(8)));
typedef unsigned int uint32;

constexpr int   kB     = 32768;
constexpr int   kT     = 50;
constexpr float kDT    = 0.01f;
constexpr float kGamma = 0.1f;
constexpr float kSigma = 0.2f;
constexpr float kTau   = 0.5f;

// 13 MFMA A-fragment images, each [64 lanes][4 dwords] f16 (lane: m=l&15,
// quad=l>>4 holds W[m][8q..8q+7]).  Phases:
// 0 y0L1  1 y0L2  2 y0L3  3 L1z  4 L1p  5 L2z  6 L2p  7 L3z  8 L3p
// 9 dx [A|B|γ]  10 fx [C|D|σ]  11 dy [Acol|Ccol]  12 dH [Bcol|Dcol]
// B-vector layouts: state=[x0..15, t@16, 1@17]; h/g=[h0..9, 1@10];
// XU=[x0..15, u0..7, 1@24]; YZ=[y0..15, zv0..15].
constexpr int kWsDwords = 13 * 256;

__device__ __forceinline__ float ftanh(float x) {
  float e = exp2f(x * 2.8853900817779268f);
  return 1.0f - 2.0f * __builtin_amdgcn_rcpf(e + 1.0f);
}

__device__ __forceinline__ uint32 pk2(float a, float b) {
  union { _Float16 h[2]; uint32 u; } z;
  z.h[0] = (_Float16)a; z.h[1] = (_Float16)b;
  return z.u;
}

__device__ __forceinline__ v4f tanh4(v4f a) {
  v4f r;
  r[0] = ftanh(a[0]); r[1] = ftanh(a[1]);
  r[2] = ftanh(a[2]); r[3] = ftanh(a[3]);
  return r;
}

union U8 { uint32 u[4]; half8 h; };

// ---------------- prep: build A-fragment images (f16) -----------------------
__global__ __launch_bounds__(256) void prep_kernel(
    const float* __restrict__ A,   const float* __restrict__ Bm,
    const float* __restrict__ Cm,  const float* __restrict__ Dm,
    const float* __restrict__ pW1, const float* __restrict__ pb1,
    const float* __restrict__ pW2, const float* __restrict__ pb2,
    const float* __restrict__ pW3, const float* __restrict__ pb3,
    const float* __restrict__ zW1, const float* __restrict__ zb1,
    const float* __restrict__ zW2, const float* __restrict__ zb2,
    const float* __restrict__ zW3, const float* __restrict__ zb3,
    const float* __restrict__ yW1, const float* __restrict__ yb1,
    const float* __restrict__ yW2, const float* __restrict__ yb2,
    const float* __restrict__ yW3, const float* __restrict__ yb3,
    uint32* __restrict__ ws, float* __restrict__ out)
{
  const int tid = threadIdx.x;
  if (tid < 2) out[tid] = 0.0f;

  auto wval = [&](int p, int m, int k) -> float {
    switch (p) {
      case 0:  // y0 L1 over state=[x, t, 1]: no t input, bias at k=17
        if (m >= 10) return 0.f;
        if (k < 16) return yW1[k * 10 + m];
        if (k == 17) return yb1[m];
        return 0.f;
      case 1:
        if (m >= 10) return 0.f;
        if (k < 10) return yW2[k * 10 + m];
        if (k == 10) return yb2[m];
        return 0.f;
      case 2:
        if (k < 10) return yW3[k * 16 + m];
        if (k == 10) return yb3[m];
        return 0.f;
      case 3:  // L1z over [x, t, 1]: W1 row0 is the t-row
        if (m >= 10) return 0.f;
        if (k < 16) return zW1[(k + 1) * 10 + m];
        if (k == 16) return zW1[m];
        if (k == 17) return zb1[m];
        return 0.f;
      case 4:
        if (m >= 10) return 0.f;
        if (k < 16) return pW1[(k + 1) * 10 + m];
        if (k == 16) return pW1[m];
        if (k == 17) return pb1[m];
        return 0.f;
      case 5:
        if (m >= 10) return 0.f;
        if (k < 10) return zW2[k * 10 + m];
        if (k == 10) return zb2[m];
        return 0.f;
      case 6:
        if (m >= 10) return 0.f;
        if (k < 10) return pW2[k * 10 + m];
        if (k == 10) return pb2[m];
        return 0.f;
      case 7:
        if (k < 10) return zW3[k * 16 + m];
        if (k == 10) return zb3[m];
        return 0.f;
      case 8:
        if (m >= 8) return 0.f;
        if (k < 10) return pW3[k * 8 + m];
        if (k == 10) return pb3[m];
        return 0.f;
      case 9:
        if (k < 16) return A[m * 16 + k];
        if (k < 24) return Bm[m * 8 + (k - 16)];
        if (k == 24) return kGamma;
        return 0.f;
      case 10:
        if (k < 16) return Cm[m * 16 + k];
        if (k < 24) return Dm[m * 8 + (k - 16)];
        if (k == 24) return kSigma;
        return 0.f;
      case 11:
        if (k < 16) return A[k * 16 + m];
        return Cm[(k - 16) * 16 + m];
      case 12:
        if (m >= 8) return 0.f;
        if (k < 16) return Bm[k * 8 + m];
        return Dm[(k - 16) * 8 + m];
    }
    return 0.f;
  };

  for (int idx = tid; idx < kWsDwords; idx += 256) {
    int p = idx >> 8, r = idx & 255;
    int lane = r >> 2, dwi = r & 3;
    int m = lane & 15, q = lane >> 4;
    int k0 = 8 * q + 2 * dwi;
    ws[idx] = pk2(wval(p, m, k0), wval(p, m, k0 + 1));
  }
}

// ---------------- main: MFMA-f16, all exchange via cross-lane shuffles ------
// C-layout (col=lane&15) and B-layout (n=lane&15) keep each element in the
// same lane-mod-16 -> the C->B transform is a permutation among lanes
// {col, col+16, col+32, col+48}: 4 __shfl of packed-f16 dwords per fragment.
// Zero LDS, zero barriers; constant slots (bias-1, t, gamma) via cndmask.
__global__ __launch_bounds__(64)
__attribute__((amdgpu_waves_per_eu(2, 2)))
void bsde_kernel(const float* __restrict__ dw, const float* __restrict__ X0,
                 const uint32* __restrict__ wsu, float* __restrict__ out)
{
  const int lane = threadIdx.x;
  const int col  = lane & 15;
  const int quad = lane >> 4;
  const int e    = blockIdx.x * 16 + col;

  half8 af[13];
#pragma unroll
  for (int p = 0; p < 13; ++p) {
    union { uint4 u; half8 h; } z;
    z.u = *(const uint4*)(wsu + p * 256 + lane * 4);
    af[p] = z.h;
  }

  const int srcA = col + ((quad & 1) << 5);          // col or col+32
  const int srcH = col + ((quad == 1) ? 32 : 0);
  const uint32 pkONE = pk2(1.f, 0.f);
  const v4f zero4 = {0.f, 0.f, 0.f, 0.f};

  auto shf = [](uint32 v, int s) -> uint32 {
    return (uint32)__shfl((int)v, s, 64);
  };

  // h/g fragment from tanh'd C-layout rows: [h0..9, 1, 0..]
  auto buildH = [&](v4f th) -> half8 {
    uint32 p0 = pk2(th[0], th[1]), p1 = pk2(th[2], th[3]);
    uint32 d0 = shf(p0, srcH);          // q0:(h0,h1)  q1:(h8,h9)
    uint32 d1 = shf(p1, srcH);          // q0:(h2,h3)
    uint32 d2 = shf(p0, col + 16);      // q0:(h4,h5)
    uint32 d3 = shf(p1, col + 16);      // q0:(h6,h7)
    U8 f;
    f.u[0] = (quad < 2)  ? d0 : 0u;
    f.u[1] = (quad == 0) ? d1 : ((quad == 1) ? pkONE : 0u);
    f.u[2] = (quad == 0) ? d2 : 0u;
    f.u[3] = (quad == 0) ? d3 : 0u;
    return f.h;
  };

  // ---- X0 + Y0 MLP ----
  v4f x4 = *(const v4f*)&X0[e * 16 + 4 * quad];   // C-layout rows 4q..4q+3
  v4f y4;
  {
    uint32 xp0 = pk2(x4[0], x4[1]), xp1 = pk2(x4[2], x4[3]);
    uint32 XD0 = shf(xp0, srcA),      XD1 = shf(xp1, srcA);
    uint32 XD2 = shf(xp0, srcA + 16), XD3 = shf(xp1, srcA + 16);
    uint32 pkT = pk2(0.f, 1.f);       // t=0, const-1
    U8 b1;
    b1.u[0] = (quad < 2) ? XD0 : ((quad == 2) ? pkT : 0u);
    b1.u[1] = (quad < 2) ? XD1 : 0u;
    b1.u[2] = (quad < 2) ? XD2 : 0u;
    b1.u[3] = (quad < 2) ? XD3 : 0u;
    v4f h = __builtin_amdgcn_mfma_f32_16x16x32_f16(af[0], b1.h, zero4, 0, 0, 0);
    half8 hf = buildH(tanh4(h));
    v4f g = __builtin_amdgcn_mfma_f32_16x16x32_f16(af[1], hf, zero4, 0, 0, 0);
    half8 gf = buildH(tanh4(g));
    y4 = __builtin_amdgcn_mfma_f32_16x16x32_f16(af[2], gf, zero4, 0, 0, 0);
  }

  float lcp = 0.0f;
  float dwv = dw[e];

  // ------------------------------- time loop -------------------------------
#pragma unroll 1
  for (int t = 0; t < kT; ++t) {
    float dwn = (t < kT - 1) ? dw[(t + 1) * kB + e] : 0.0f;
    const float tv = (float)t * kDT;
    const float wt = (t == 0 || t == kT - 1) ? 1.0f : 2.0f;

    // Pack current state, build shuffled x/y parts
    uint32 xp0 = pk2(x4[0], x4[1]), xp1 = pk2(x4[2], x4[3]);
    uint32 yp0 = pk2(y4[0], y4[1]), yp1 = pk2(y4[2], y4[3]);
    uint32 XD0 = shf(xp0, srcA),      XD1 = shf(xp1, srcA);
    uint32 XD2 = shf(xp0, srcA + 16), XD3 = shf(xp1, srcA + 16);
    uint32 YD0 = shf(yp0, srcA),      YD1 = shf(yp1, srcA);
    uint32 YD2 = shf(yp0, srcA + 16), YD3 = shf(yp1, srcA + 16);

    // B1 = [x, t, 1]
    uint32 pkT = pk2(tv, 1.f);
    U8 b1;
    b1.u[0] = (quad < 2) ? XD0 : ((quad == 2) ? pkT : 0u);
    b1.u[1] = (quad < 2) ? XD1 : 0u;
    b1.u[2] = (quad < 2) ? XD2 : 0u;
    b1.u[3] = (quad < 2) ? XD3 : 0u;

    // L1 both MLPs
    v4f hz = __builtin_amdgcn_mfma_f32_16x16x32_f16(af[3], b1.h, zero4, 0, 0, 0);
    v4f hp = __builtin_amdgcn_mfma_f32_16x16x32_f16(af[4], b1.h, zero4, 0, 0, 0);
    half8 hzf = buildH(tanh4(hz));
    half8 hpf = buildH(tanh4(hp));

    // L2
    v4f gz = __builtin_amdgcn_mfma_f32_16x16x32_f16(af[5], hzf, zero4, 0, 0, 0);
    v4f gp = __builtin_amdgcn_mfma_f32_16x16x32_f16(af[6], hpf, zero4, 0, 0, 0);
    half8 gzf = buildH(tanh4(gz));
    half8 gpf = buildH(tanh4(gp));

    // L3
    v4f zv = __builtin_amdgcn_mfma_f32_16x16x32_f16(af[7], gzf, zero4, 0, 0, 0);
    v4f uu = __builtin_amdgcn_mfma_f32_16x16x32_f16(af[8], gpf, zero4, 0, 0, 0);

    // XU = [x, u, 1] ; YZ = [y, zv]
    uint32 up0 = pk2(uu[0], uu[1]), up1 = pk2(uu[2], uu[3]);
    uint32 zp0 = pk2(zv[0], zv[1]), zp1 = pk2(zv[2], zv[3]);
    uint32 UD0 = shf(up0, col),      UD1 = shf(up1, col);
    uint32 UD2 = shf(up0, col + 16), UD3 = shf(up1, col + 16);
    uint32 ZD0 = shf(zp0, srcA),      ZD1 = shf(zp1, srcA);
    uint32 ZD2 = shf(zp0, srcA + 16), ZD3 = shf(zp1, srcA + 16);

    U8 xu, yz;
    xu.u[0] = (quad < 2) ? XD0 : ((quad == 2) ? UD0 : pkONE);
    xu.u[1] = (quad < 2) ? XD1 : ((quad == 2) ? UD1 : 0u);
    xu.u[2] = (quad < 2) ? XD2 : ((quad == 2) ? UD2 : 0u);
    xu.u[3] = (quad < 2) ? XD3 : ((quad == 2) ? UD3 : 0u);
    yz.u[0] = (quad < 2) ? YD0 : ZD0;
    yz.u[1] = (quad < 2) ? YD1 : ZD1;
    yz.u[2] = (quad < 2) ? YD2 : ZD2;
    yz.u[3] = (quad < 2) ? YD3 : ZD3;

    v4f dx = __builtin_amdgcn_mfma_f32_16x16x32_f16(af[9],  xu.h, zero4, 0, 0, 0);
    v4f fx = __builtin_amdgcn_mfma_f32_16x16x32_f16(af[10], xu.h, zero4, 0, 0, 0);
    v4f dy = __builtin_amdgcn_mfma_f32_16x16x32_f16(af[11], yz.h, zero4, 0, 0, 0);
    v4f dh = __builtin_amdgcn_mfma_f32_16x16x32_f16(af[12], yz.h, zero4, 0, 0, 0);

    float ss = 0.0f;
    v4f Xn, Yn;
#pragma unroll
    for (int r = 0; r < 4; ++r) {
      Xn[r] = x4[r] + kDT * dx[r] + dwv * fx[r];
      Yn[r] = y4[r] - kDT * (dy[r] + x4[r]) + dwv * zv[r];
      float d = dh[r] + uu[r];            // rows>=8: both 0
      ss += d * d;
    }
    lcp += (0.5f * kDT * kTau * kTau) * wt * ss;
    x4 = Xn; y4 = Yn;
    dwv = dwn;
  }

  // ---- losses ----
  float bp = 0.0f;
#pragma unroll
  for (int r = 0; r < 4; ++r) { float d = y4[r] - x4[r]; bp += d * d; }

#pragma unroll
  for (int s = 32; s > 0; s >>= 1) {
    bp  += __shfl_down(bp,  s, 64);
    lcp += __shfl_down(lcp, s, 64);
  }
  if (lane == 0) {
    atomicAdd(&out[0], bp  * (1.0f / (float)kB));
    atomicAdd(&out[1], lcp * (1.0f / (float)kB));
  }
}

} // namespace

extern "C" void kernel_launch(void* const* d_in, const int* in_sizes, int n_in,
                              void* d_out, int out_size, void* d_ws, size_t ws_size,
                              hipStream_t stream) {
  (void)in_sizes; (void)n_in; (void)ws_size; (void)out_size;

  const float* dw  = (const float*)d_in[0];
  const float* X0  = (const float*)d_in[1];
  const float* A   = (const float*)d_in[2];
  const float* Bm  = (const float*)d_in[3];
  const float* Cm  = (const float*)d_in[4];
  const float* Dm  = (const float*)d_in[5];
  const float* pW1 = (const float*)d_in[6];
  const float* pb1 = (const float*)d_in[7];
  const float* pW2 = (const float*)d_in[8];
  const float* pb2 = (const float*)d_in[9];
  const float* pW3 = (const float*)d_in[10];
  const float* pb3 = (const float*)d_in[11];
  const float* zW1 = (const float*)d_in[12];
  const float* zb1 = (const float*)d_in[13];
  const float* zW2 = (const float*)d_in[14];
  const float* zb2 = (const float*)d_in[15];
  const float* zW3 = (const float*)d_in[16];
  const float* zb3 = (const float*)d_in[17];
  const float* yW1 = (const float*)d_in[18];
  const float* yb1 = (const float*)d_in[19];
  const float* yW2 = (const float*)d_in[20];
  const float* yb2 = (const float*)d_in[21];
  const float* yW3 = (const float*)d_in[22];
  const float* yb3 = (const float*)d_in[23];
  float* out = (float*)d_out;
  unsigned int* ws = (unsigned int*)d_ws;

  prep_kernel<<<1, 256, 0, stream>>>(
      A, Bm, Cm, Dm,
      pW1, pb1, pW2, pb2, pW3, pb3,
      zW1, zb1, zW2, zb2, zW3, zb3,
      yW1, yb1, yW2, yb2, yW3, yb3, ws, out);

  bsde_kernel<<<kB / 16, 64, 0, stream>>>(dw, X0, ws, out);
}

// Round 15
// 214.983 us; speedup vs baseline: 1.6173x; 1.0086x over previous
//
#include <hip/hip_runtime.h>

namespace {

typedef float v4f __attribute__((ext_vector_type(4)));
typedef _Float16 half8 __attribute__((ext_vector_type(8)));
typedef unsigned int uint32;

constexpr int   kB     = 32768;
constexpr int   kT     = 50;
constexpr float kDT    = 0.01f;
constexpr float kGamma = 0.1f;
constexpr float kSigma = 0.2f;
constexpr float kTau   = 0.5f;
constexpr float kA     = 2.8853900817779268f;   // 2*log2(e)

// 13 MFMA A-fragment images, each [64 lanes][4 dwords] f16.
// ACTIVATION-FOLDED: act(v) = rcp(exp2(v)+1) = r; tanh = 1-2r absorbed into
// the next layer's weights (W' = -2W, b' = b + sum(W)); layers feeding another
// activation additionally pre-scaled by kA.
// Phases: 0 y0L1  1 y0L2  2 y0L3  3 L1z  4 L1p  5 L2z  6 L2p  7 L3z  8 L3p
// 9 dx [A|B|γ]  10 fx [C|D|σ]  11 dy [Acol|Ccol]  12 dH [Bcol|Dcol]
constexpr int kWsDwords = 13 * 256;

__device__ __forceinline__ float fact(float x) {   // rcp(exp2(x)+1)
  return __builtin_amdgcn_rcpf(exp2f(x) + 1.0f);
}

__device__ __forceinline__ uint32 pk2(float a, float b) {
  union { _Float16 h[2]; uint32 u; } z;
  z.h[0] = (_Float16)a; z.h[1] = (_Float16)b;
  return z.u;
}

__device__ __forceinline__ v4f act4(v4f a) {
  v4f r;
  r[0] = fact(a[0]); r[1] = fact(a[1]);
  r[2] = fact(a[2]); r[3] = fact(a[3]);
  return r;
}

union U8 { uint32 u[4]; half8 h; };

// ---------------- prep: build folded A-fragment images (f16) ----------------
__global__ __launch_bounds__(256) void prep_kernel(
    const float* __restrict__ A,   const float* __restrict__ Bm,
    const float* __restrict__ Cm,  const float* __restrict__ Dm,
    const float* __restrict__ pW1, const float* __restrict__ pb1,
    const float* __restrict__ pW2, const float* __restrict__ pb2,
    const float* __restrict__ pW3, const float* __restrict__ pb3,
    const float* __restrict__ zW1, const float* __restrict__ zb1,
    const float* __restrict__ zW2, const float* __restrict__ zb2,
    const float* __restrict__ zW3, const float* __restrict__ zb3,
    const float* __restrict__ yW1, const float* __restrict__ yb1,
    const float* __restrict__ yW2, const float* __restrict__ yb2,
    const float* __restrict__ yW3, const float* __restrict__ yb3,
    uint32* __restrict__ ws, float* __restrict__ out)
{
  const int tid = threadIdx.x;
  if (tid < 2) out[tid] = 0.0f;

  auto sum10 = [](const float* W, int stride, int m) {
    float s = 0.f;
    for (int j = 0; j < 10; ++j) s += W[j * stride + m];
    return s;
  };

  auto wval = [&](int p, int m, int k) -> float {
    switch (p) {
      case 0:  // y0 L1 over [x, t, 1], pre-scaled by kA
        if (m >= 10) return 0.f;
        if (k < 16) return kA * yW1[k * 10 + m];
        if (k == 17) return kA * yb1[m];
        return 0.f;
      case 1:  // y0 L2: input r -> W' = -2*kA*W, b' = kA*(b + sumW)
        if (m >= 10) return 0.f;
        if (k < 10) return -2.f * kA * yW2[k * 10 + m];
        if (k == 10) return kA * (yb2[m] + sum10(yW2, 10, m));
        return 0.f;
      case 2:  // y0 L3: no activation after -> W' = -2W, b' = b + sumW
        if (k < 10) return -2.f * yW3[k * 16 + m];
        if (k == 10) return yb3[m] + sum10(yW3, 16, m);
        return 0.f;
      case 3:  // L1z over [x, t, 1], pre-scaled kA; W1 row0 is t-row
        if (m >= 10) return 0.f;
        if (k < 16) return kA * zW1[(k + 1) * 10 + m];
        if (k == 16) return kA * zW1[m];
        if (k == 17) return kA * zb1[m];
        return 0.f;
      case 4:
        if (m >= 10) return 0.f;
        if (k < 16) return kA * pW1[(k + 1) * 10 + m];
        if (k == 16) return kA * pW1[m];
        if (k == 17) return kA * pb1[m];
        return 0.f;
      case 5:
        if (m >= 10) return 0.f;
        if (k < 10) return -2.f * kA * zW2[k * 10 + m];
        if (k == 10) return kA * (zb2[m] + sum10(zW2, 10, m));
        return 0.f;
      case 6:
        if (m >= 10) return 0.f;
        if (k < 10) return -2.f * kA * pW2[k * 10 + m];
        if (k == 10) return kA * (pb2[m] + sum10(pW2, 10, m));
        return 0.f;
      case 7:
        if (k < 10) return -2.f * zW3[k * 16 + m];
        if (k == 10) return zb3[m] + sum10(zW3, 16, m);
        return 0.f;
      case 8:
        if (m >= 8) return 0.f;
        if (k < 10) return -2.f * pW3[k * 8 + m];
        if (k == 10) return pb3[m] + sum10(pW3, 8, m);
        return 0.f;
      case 9:
        if (k < 16) return A[m * 16 + k];
        if (k < 24) return Bm[m * 8 + (k - 16)];
        if (k == 24) return kGamma;
        return 0.f;
      case 10:
        if (k < 16) return Cm[m * 16 + k];
        if (k < 24) return Dm[m * 8 + (k - 16)];
        if (k == 24) return kSigma;
        return 0.f;
      case 11:
        if (k < 16) return A[k * 16 + m];
        return Cm[(k - 16) * 16 + m];
      case 12:
        if (m >= 8) return 0.f;
        if (k < 16) return Bm[k * 8 + m];
        return Dm[(k - 16) * 8 + m];
    }
    return 0.f;
  };

  for (int idx = tid; idx < kWsDwords; idx += 256) {
    int p = idx >> 8, r = idx & 255;
    int lane = r >> 2, dwi = r & 3;
    int m = lane & 15, q = lane >> 4;
    int k0 = 8 * q + 2 * dwi;
    ws[idx] = pk2(wval(p, m, k0), wval(p, m, k0 + 1));
  }
}

// ---------------- main: MFMA-f16, shuffle exchange, folded activations ------
__global__ __launch_bounds__(64)
__attribute__((amdgpu_waves_per_eu(2, 2)))
void bsde_kernel(const float* __restrict__ dw, const float* __restrict__ X0,
                 const uint32* __restrict__ wsu, float* __restrict__ out)
{
  const int lane = threadIdx.x;
  const int col  = lane & 15;
  const int quad = lane >> 4;
  const int e    = blockIdx.x * 16 + col;

  half8 af[13];
#pragma unroll
  for (int p = 0; p < 13; ++p) {
    union { uint4 u; half8 h; } z;
    z.u = *(const uint4*)(wsu + p * 256 + lane * 4);
    af[p] = z.h;
  }

  const int srcA  = col + ((quad & 1) << 5);           // col or col+32
  const int addrH = col + ((quad == 0) ? 16 : 32);     // buildH shared-bperm addr
  const uint32 pkONE = pk2(1.f, 0.f);
  const v4f zero4 = {0.f, 0.f, 0.f, 0.f};

  auto shf = [](uint32 v, int s) -> uint32 {
    return (uint32)__shfl((int)v, s, 64);
  };

  // h/g fragment [r0..r9, 1, 0..] from C-layout act values — 2 bpermutes:
  // quad0 slots 0,1 are LOCAL packs; bpA serves q0:(h4,h5) AND q1:(h8,h9)
  // via per-lane address.
  auto buildH = [&](v4f th) -> half8 {
    uint32 lp0 = pk2(th[0], th[1]);
    uint32 lp1 = pk2(th[2], th[3]);
    uint32 bpA = shf(lp0, addrH);
    uint32 bpB = shf(lp1, addrH);
    U8 f;
    f.u[0] = (quad == 0) ? lp0 : ((quad == 1) ? bpA : 0u);
    f.u[1] = (quad == 0) ? lp1 : ((quad == 1) ? pkONE : 0u);
    f.u[2] = (quad == 0) ? bpA : 0u;
    f.u[3] = (quad == 0) ? bpB : 0u;
    return f.h;
  };

  // ---- X0 + Y0 MLP ----
  v4f x4 = *(const v4f*)&X0[e * 16 + 4 * quad];   // C-layout rows 4q..4q+3
  v4f y4;
  {
    uint32 xp0 = pk2(x4[0], x4[1]), xp1 = pk2(x4[2], x4[3]);
    uint32 XD0 = shf(xp0, srcA),      XD1 = shf(xp1, srcA);
    uint32 XD2 = shf(xp0, srcA + 16), XD3 = shf(xp1, srcA + 16);
    uint32 pkT = pk2(0.f, 1.f);
    U8 b1;
    b1.u[0] = (quad < 2) ? XD0 : ((quad == 2) ? pkT : 0u);
    b1.u[1] = (quad < 2) ? XD1 : 0u;
    b1.u[2] = (quad < 2) ? XD2 : 0u;
    b1.u[3] = (quad < 2) ? XD3 : 0u;
    v4f h = __builtin_amdgcn_mfma_f32_16x16x32_f16(af[0], b1.h, zero4, 0, 0, 0);
    half8 hf = buildH(act4(h));
    v4f g = __builtin_amdgcn_mfma_f32_16x16x32_f16(af[1], hf, zero4, 0, 0, 0);
    half8 gf = buildH(act4(g));
    y4 = __builtin_amdgcn_mfma_f32_16x16x32_f16(af[2], gf, zero4, 0, 0, 0);
  }

  float lcp = 0.0f;
  float dwv = dw[e];

  // ------------------------------- time loop -------------------------------
#pragma unroll 1
  for (int t = 0; t < kT; ++t) {
    float dwn = (t < kT - 1) ? dw[(t + 1) * kB + e] : 0.0f;
    const float tv = (float)t * kDT;
    const float wt = (t == 0 || t == kT - 1) ? 1.0f : 2.0f;

    uint32 xp0 = pk2(x4[0], x4[1]), xp1 = pk2(x4[2], x4[3]);
    uint32 yp0 = pk2(y4[0], y4[1]), yp1 = pk2(y4[2], y4[3]);
    uint32 XD0 = shf(xp0, srcA),      XD1 = shf(xp1, srcA);
    uint32 XD2 = shf(xp0, srcA + 16), XD3 = shf(xp1, srcA + 16);
    uint32 YD0 = shf(yp0, srcA),      YD1 = shf(yp1, srcA);
    uint32 YD2 = shf(yp0, srcA + 16), YD3 = shf(yp1, srcA + 16);

    // B1 = [x, t, 1]  (t pre-scaled by kA via weights; raw t here)
    uint32 pkT = pk2(tv, 1.f);
    U8 b1;
    b1.u[0] = (quad < 2) ? XD0 : ((quad == 2) ? pkT : 0u);
    b1.u[1] = (quad < 2) ? XD1 : 0u;
    b1.u[2] = (quad < 2) ? XD2 : 0u;
    b1.u[3] = (quad < 2) ? XD3 : 0u;

    // L1 both MLPs
    v4f hz = __builtin_amdgcn_mfma_f32_16x16x32_f16(af[3], b1.h, zero4, 0, 0, 0);
    v4f hp = __builtin_amdgcn_mfma_f32_16x16x32_f16(af[4], b1.h, zero4, 0, 0, 0);
    half8 hzf = buildH(act4(hz));
    half8 hpf = buildH(act4(hp));

    // L2
    v4f gz = __builtin_amdgcn_mfma_f32_16x16x32_f16(af[5], hzf, zero4, 0, 0, 0);
    v4f gp = __builtin_amdgcn_mfma_f32_16x16x32_f16(af[6], hpf, zero4, 0, 0, 0);
    half8 gzf = buildH(act4(gz));
    half8 gpf = buildH(act4(gp));

    // L3
    v4f zv = __builtin_amdgcn_mfma_f32_16x16x32_f16(af[7], gzf, zero4, 0, 0, 0);
    v4f uu = __builtin_amdgcn_mfma_f32_16x16x32_f16(af[8], gpf, zero4, 0, 0, 0);

    // XU = [x, u, 1] ; YZ = [y, zv]
    uint32 up0 = pk2(uu[0], uu[1]), up1 = pk2(uu[2], uu[3]);
    uint32 zp0 = pk2(zv[0], zv[1]), zp1 = pk2(zv[2], zv[3]);
    uint32 UD0 = shf(up0, col),      UD1 = shf(up1, col);
    uint32 UD2 = shf(up0, col + 16), UD3 = shf(up1, col + 16);
    uint32 ZD0 = shf(zp0, srcA),      ZD1 = shf(zp1, srcA);
    uint32 ZD2 = shf(zp0, srcA + 16), ZD3 = shf(zp1, srcA + 16);

    U8 xu, yz;
    xu.u[0] = (quad < 2) ? XD0 : ((quad == 2) ? UD0 : pkONE);
    xu.u[1] = (quad < 2) ? XD1 : ((quad == 2) ? UD1 : 0u);
    xu.u[2] = (quad < 2) ? XD2 : ((quad == 2) ? UD2 : 0u);
    xu.u[3] = (quad < 2) ? XD3 : ((quad == 2) ? UD3 : 0u);
    yz.u[0] = (quad < 2) ? YD0 : ZD0;
    yz.u[1] = (quad < 2) ? YD1 : ZD1;
    yz.u[2] = (quad < 2) ? YD2 : ZD2;
    yz.u[3] = (quad < 2) ? YD3 : ZD3;

    v4f dx = __builtin_amdgcn_mfma_f32_16x16x32_f16(af[9],  xu.h, zero4, 0, 0, 0);
    v4f fx = __builtin_amdgcn_mfma_f32_16x16x32_f16(af[10], xu.h, zero4, 0, 0, 0);
    v4f dy = __builtin_amdgcn_mfma_f32_16x16x32_f16(af[11], yz.h, zero4, 0, 0, 0);
    v4f dh = __builtin_amdgcn_mfma_f32_16x16x32_f16(af[12], yz.h, zero4, 0, 0, 0);

    float ss = 0.0f;
    v4f Xn, Yn;
#pragma unroll
    for (int r = 0; r < 4; ++r) {
      Xn[r] = x4[r] + kDT * dx[r] + dwv * fx[r];
      Yn[r] = y4[r] - kDT * (dy[r] + x4[r]) + dwv * zv[r];
      float d = dh[r] + uu[r];            // rows>=8: both 0
      ss += d * d;
    }
    lcp += (0.5f * kDT * kTau * kTau) * wt * ss;
    x4 = Xn; y4 = Yn;
    dwv = dwn;
  }

  // ---- losses ----
  float bp = 0.0f;
#pragma unroll
  for (int r = 0; r < 4; ++r) { float d = y4[r] - x4[r]; bp += d * d; }

#pragma unroll
  for (int s = 32; s > 0; s >>= 1) {
    bp  += __shfl_down(bp,  s, 64);
    lcp += __shfl_down(lcp, s, 64);
  }
  if (lane == 0) {
    atomicAdd(&out[0], bp  * (1.0f / (float)kB));
    atomicAdd(&out[1], lcp * (1.0f / (float)kB));
  }
}

} // namespace

extern "C" void kernel_launch(void* const* d_in, const int* in_sizes, int n_in,
                              void* d_out, int out_size, void* d_ws, size_t ws_size,
                              hipStream_t stream) {
  (void)in_sizes; (void)n_in; (void)ws_size; (void)out_size;

  const float* dw  = (const float*)d_in[0];
  const float* X0  = (const float*)d_in[1];
  const float* A   = (const float*)d_in[2];
  const float* Bm  = (const float*)d_in[3];
  const float* Cm  = (const float*)d_in[4];
  const float* Dm  = (const float*)d_in[5];
  const float* pW1 = (const float*)d_in[6];
  const float* pb1 = (const float*)d_in[7];
  const float* pW2 = (const float*)d_in[8];
  const float* pb2 = (const float*)d_in[9];
  const float* pW3 = (const float*)d_in[10];
  const float* pb3 = (const float*)d_in[11];
  const float* zW1 = (const float*)d_in[12];
  const float* zb1 = (const float*)d_in[13];
  const float* zW2 = (const float*)d_in[14];
  const float* zb2 = (const float*)d_in[15];
  const float* zW3 = (const float*)d_in[16];
  const float* zb3 = (const float*)d_in[17];
  const float* yW1 = (const float*)d_in[18];
  const float* yb1 = (const float*)d_in[19];
  const float* yW2 = (const float*)d_in[20];
  const float* yb2 = (const float*)d_in[21];
  const float* yW3 = (const float*)d_in[22];
  const float* yb3 = (const float*)d_in[23];
  float* out = (float*)d_out;
  unsigned int* ws = (unsigned int*)d_ws;

  prep_kernel<<<1, 256, 0, stream>>>(
      A, Bm, Cm, Dm,
      pW1, pb1, pW2, pb2, pW3, pb3,
      zW1, zb1, zW2, zb2, zW3, zb3,
      yW1, yb1, yW2, yb2, yW3, yb3, ws, out);

  bsde_kernel<<<kB / 16, 64, 0, stream>>>(dw, X0, ws, out);
}